// Round 1
// baseline (1115.343 us; speedup 1.0000x reference)
//
#include <hip/hip_runtime.h>
#include <math.h>

#define B_ 32
#define N_ 128
#define E_ 16384
#define EPS_ 1e-5f

// ---- ws layout (float offsets) ----
#define WS_STATS_E 0        // 144 accумs, stride 16 floats (line-padded)
#define WS_STATS_H 2304
#define WS_MAGG    4608     // B*N*72
#define WS_AGG     299520   // B*N*4
#define WS_CNT     315904   // B*N
#define WS_ZERO_END 320000
#define WS_AE      320000
#define WS_BE      320072
#define WS_AH      320144
#define WS_BH      320216
#define WS_WX1T    320288   // 72*72 transposed
#define WS_ZH1     325472   // B*N*72
// total = 620384 floats (~2.37 MB)

#define HOUT_OFF 0
#define XOUT_OFF 294912
#define M_OFF    311296

// -------------------- small prep: transpose W_x1 --------------------
__global__ void k_transpose(const float* __restrict__ Wx1, float* __restrict__ WT) {
    int idx = blockIdx.x * 256 + threadIdx.x;
    if (idx < 72 * 72) {
        int r = idx / 72, c = idx - r * 72;
        WT[c * 72 + r] = Wx1[idx];
    }
}

// -------------------- kernel 1: feat @ W_e1 -> z1 (+BN stats) --------------------
__global__ __launch_bounds__(256) void k_edge1(
    const float* __restrict__ h, const float* __restrict__ x,
    const int* __restrict__ ei, const int* __restrict__ ej,
    const float* __restrict__ We1,
    float* __restrict__ z1,          // = d_out m region
    float* __restrict__ gstats)
{
    __shared__ float ls[144 * 33];
    int t = threadIdx.x;
    for (int idx = t; idx < 144 * 33; idx += 256) ls[idx] = 0.f;
    __syncthreads();

    int eg = blockIdx.x * 256 + t;           // < B*E = 524288
    int b = eg >> 14;                        // E = 2^14
    int i = ei[eg], j = ej[eg];
    int ri = b * N_ + i, rj = b * N_ + j;

    float4 xi = *(const float4*)(x + ri * 4);
    float4 xj = *(const float4*)(x + rj * 4);
    float xdx = xi.x - xj.x, xdy = xi.y - xj.y, xdz = xi.z - xj.z, xdw = xi.w - xj.w;
    float nsq = xdx * xdx - xdy * xdy - xdz * xdz - xdw * xdw;
    float dsq = xi.x * xj.x - xi.y * xj.y - xi.z * xj.z - xi.w * xj.w;
    float norms = copysignf(log1pf(fabsf(nsq)), nsq);
    float dots  = copysignf(log1pf(fabsf(dsq)), dsq);

    float acc[72];
    {
        const float* w144 = We1 + 144 * 72;
        const float* w145 = We1 + 145 * 72;
#pragma unroll
        for (int c = 0; c < 72; ++c)
            acc[c] = fmaf(norms, w144[c], dots * w145[c]);
    }
    const float4* hi4 = (const float4*)(h + ri * 72);
    const float4* hj4 = (const float4*)(h + rj * 72);
    for (int kc = 0; kc < 18; ++kc) {
        float4 a = hi4[kc];
        const float* wr = We1 + (kc * 4) * 72;
#pragma unroll
        for (int c = 0; c < 72; ++c)
            acc[c] = fmaf(a.x, wr[c], fmaf(a.y, wr[72 + c], fmaf(a.z, wr[144 + c], fmaf(a.w, wr[216 + c], acc[c]))));
    }
    for (int kc = 0; kc < 18; ++kc) {
        float4 a = hj4[kc];
        const float* wr = We1 + (72 + kc * 4) * 72;
#pragma unroll
        for (int c = 0; c < 72; ++c)
            acc[c] = fmaf(a.x, wr[c], fmaf(a.y, wr[72 + c], fmaf(a.z, wr[144 + c], fmaf(a.w, wr[216 + c], acc[c]))));
    }

    float4* zr = (float4*)(z1 + (long)eg * 72);
#pragma unroll
    for (int kc = 0; kc < 18; ++kc)
        zr[kc] = make_float4(acc[4 * kc], acc[4 * kc + 1], acc[4 * kc + 2], acc[4 * kc + 3]);

    // BN stats: LDS slot bins (bank = (c+slot)%32, slot=t&31 -> conflict-free)
    int slot = t & 31;
#pragma unroll
    for (int c = 0; c < 72; ++c) {
        atomicAdd(&ls[c * 33 + slot], acc[c]);
        atomicAdd(&ls[(72 + c) * 33 + slot], acc[c] * acc[c]);
    }
    __syncthreads();
    for (int c = t; c < 144; c += 256) {
        float s = 0.f;
        for (int q = 0; q < 32; ++q) s += ls[c * 33 + q];
        atomicAdd(&gstats[c * 16], s);
    }
}

// -------------------- BN finalize --------------------
__global__ void k_fin(const float* __restrict__ gstats, const float* __restrict__ g,
                      const float* __restrict__ be, float* __restrict__ A,
                      float* __restrict__ Bv, float Minv)
{
    int c = threadIdx.x;
    if (c < 72) {
        float s = gstats[c * 16], sq = gstats[(72 + c) * 16];
        float mu = s * Minv;
        float var = sq * Minv - mu * mu;
        float inv = rsqrtf(var + EPS_);
        float a = g[c] * inv;
        A[c] = a;
        Bv[c] = be[c] - mu * a;
    }
}

// -------------------- kernel 3: BN->relu->We2->gate->m; phi_x; segment sums --------------------
__global__ __launch_bounds__(256) void k_edge2(
    const float* __restrict__ x,
    const int* __restrict__ ei, const int* __restrict__ ej,
    const float* __restrict__ We2, const float* __restrict__ be2,
    const float* __restrict__ Wm, const float* __restrict__ bm,
    const float* __restrict__ bx1, const float* __restrict__ Wx1T,
    const float* __restrict__ Wx2,
    const float* __restrict__ Ae, const float* __restrict__ Be,
    float* m_out,                       // z1 in, m out (in place, same thread)
    float* __restrict__ magg, float* __restrict__ agg, float* __restrict__ cnt)
{
    __shared__ float lmagg[128 * 73];
    __shared__ float lagg[128 * 5];
    __shared__ float lcnt[128];
    int t = threadIdx.x;
    for (int idx = t; idx < 128 * 73; idx += 256) lmagg[idx] = 0.f;
    for (int idx = t; idx < 128 * 5; idx += 256) lagg[idx] = 0.f;
    if (t < 128) lcnt[t] = 0.f;
    __syncthreads();

    int b = blockIdx.x >> 4;
    int chunk = blockIdx.x & 15;

    for (int it = 0; it < 4; ++it) {
        int el = chunk * 1024 + it * 256 + t;
        int eg = b * E_ + el;
        int i = ei[eg], j = ej[eg];
        float4 xi = *(const float4*)(x + (b * N_ + i) * 4);
        float4 xj = *(const float4*)(x + (b * N_ + j) * 4);
        float xdx = xi.x - xj.x, xdy = xi.y - xj.y, xdz = xi.z - xj.z, xdw = xi.w - xj.w;

        // ---- z2 = relu( relu(BN(z1)) @ We2 + be2 ) ----
        float acc[72];
#pragma unroll
        for (int c = 0; c < 72; ++c) acc[c] = be2[c];
        const float4* zr = (const float4*)(m_out + (long)eg * 72);
        for (int kc = 0; kc < 18; ++kc) {
            float4 v = zr[kc];
            int k0 = kc * 4;
            float z0 = fmaxf(fmaf(v.x, Ae[k0],     Be[k0]),     0.f);
            float z1v = fmaxf(fmaf(v.y, Ae[k0 + 1], Be[k0 + 1]), 0.f);
            float z2v = fmaxf(fmaf(v.z, Ae[k0 + 2], Be[k0 + 2]), 0.f);
            float z3v = fmaxf(fmaf(v.w, Ae[k0 + 3], Be[k0 + 3]), 0.f);
            const float* w0 = We2 + k0 * 72;
#pragma unroll
            for (int c = 0; c < 72; ++c)
                acc[c] = fmaf(z0, w0[c], fmaf(z1v, w0[72 + c], fmaf(z2v, w0[144 + c], fmaf(z3v, w0[216 + c], acc[c]))));
        }
        float wdot = bm[0];
#pragma unroll
        for (int c = 0; c < 72; ++c) {
            acc[c] = fmaxf(acc[c], 0.f);
            wdot = fmaf(acc[c], Wm[c], wdot);
        }
        float wsig = 1.f / (1.f + expf(-wdot));
#pragma unroll
        for (int c = 0; c < 72; ++c) acc[c] *= wsig;   // acc = m

        float4* zw = (float4*)(m_out + (long)eg * 72);
#pragma unroll
        for (int kc = 0; kc < 18; ++kc)
            zw[kc] = make_float4(acc[4 * kc], acc[4 * kc + 1], acc[4 * kc + 2], acc[4 * kc + 3]);

        // ---- phi_x: phix = relu(m @ Wx1 + bx1) . Wx2 (Wx1T: [c2][c]) ----
        float phix = 0.f;
        for (int c2c = 0; c2c < 18; ++c2c) {
            int c20 = c2c * 4;
            float t0 = bx1[c20], t1 = bx1[c20 + 1], t2 = bx1[c20 + 2], t3 = bx1[c20 + 3];
            const float* w0 = Wx1T + c20 * 72;
#pragma unroll
            for (int c = 0; c < 72; ++c) {
                t0 = fmaf(acc[c], w0[c], t0);
                t1 = fmaf(acc[c], w0[72 + c], t1);
                t2 = fmaf(acc[c], w0[144 + c], t2);
                t3 = fmaf(acc[c], w0[216 + c], t3);
            }
            phix = fmaf(fmaxf(t0, 0.f), Wx2[c20], phix);
            phix = fmaf(fmaxf(t1, 0.f), Wx2[c20 + 1], phix);
            phix = fmaf(fmaxf(t2, 0.f), Wx2[c20 + 2], phix);
            phix = fmaf(fmaxf(t3, 0.f), Wx2[c20 + 3], phix);
        }
        float trx = fminf(fmaxf(xdx * phix, -100.f), 100.f);
        float try_ = fminf(fmaxf(xdy * phix, -100.f), 100.f);
        float trz = fminf(fmaxf(xdz * phix, -100.f), 100.f);
        float trw = fminf(fmaxf(xdw * phix, -100.f), 100.f);

        atomicAdd(&lcnt[i], 1.f);
        atomicAdd(&lagg[i * 5 + 0], trx);
        atomicAdd(&lagg[i * 5 + 1], try_);
        atomicAdd(&lagg[i * 5 + 2], trz);
        atomicAdd(&lagg[i * 5 + 3], trw);
        int base = i * 73;
#pragma unroll
        for (int c = 0; c < 72; ++c)
            atomicAdd(&lmagg[base + c], acc[c]);
    }
    __syncthreads();

    int nb = b * N_;
    for (int idx = t; idx < 128 * 72; idx += 256) {
        int n = idx / 72, c = idx - n * 72;
        float v = lmagg[n * 73 + c];
        if (v != 0.f) atomicAdd(&magg[(nb + n) * 72 + c], v);
    }
    for (int idx = t; idx < 128 * 4; idx += 256) {
        int n = idx >> 2, d = idx & 3;
        float v = lagg[n * 5 + d];
        if (v != 0.f) atomicAdd(&agg[(nb + n) * 4 + d], v);
    }
    if (t < 128) {
        float v = lcnt[t];
        if (v != 0.f) atomicAdd(&cnt[nb + t], v);
    }
}

// -------------------- kernel 4a: cat @ W_h1 + b_h1 -> zh1 (+BN stats) --------------------
__global__ __launch_bounds__(256) void k_node1(
    const float* __restrict__ h, const float* __restrict__ magg,
    const float* __restrict__ attr, const float* __restrict__ Wh1,
    const float* __restrict__ bh1,
    float* __restrict__ zh1, float* __restrict__ gstats)
{
    __shared__ float ls[144 * 33];
    int t = threadIdx.x;
    for (int idx = t; idx < 144 * 33; idx += 256) ls[idx] = 0.f;
    __syncthreads();

    int row = blockIdx.x * 256 + t;   // < 4096
    float acc[72];
#pragma unroll
    for (int c = 0; c < 72; ++c) acc[c] = bh1[c];

    const float4* h4 = (const float4*)(h + row * 72);
    for (int kc = 0; kc < 18; ++kc) {
        float4 a = h4[kc];
        const float* wr = Wh1 + (kc * 4) * 72;
#pragma unroll
        for (int c = 0; c < 72; ++c)
            acc[c] = fmaf(a.x, wr[c], fmaf(a.y, wr[72 + c], fmaf(a.z, wr[144 + c], fmaf(a.w, wr[216 + c], acc[c]))));
    }
    const float4* mg4 = (const float4*)(magg + row * 72);
    for (int kc = 0; kc < 18; ++kc) {
        float4 a = mg4[kc];
        const float* wr = Wh1 + ((72 + kc * 4)) * 72;
#pragma unroll
        for (int c = 0; c < 72; ++c)
            acc[c] = fmaf(a.x, wr[c], fmaf(a.y, wr[72 + c], fmaf(a.z, wr[144 + c], fmaf(a.w, wr[216 + c], acc[c]))));
    }
    const float4* at4 = (const float4*)(attr + row * 8);
    for (int kc = 0; kc < 2; ++kc) {
        float4 a = at4[kc];
        const float* wr = Wh1 + ((144 + kc * 4)) * 72;
#pragma unroll
        for (int c = 0; c < 72; ++c)
            acc[c] = fmaf(a.x, wr[c], fmaf(a.y, wr[72 + c], fmaf(a.z, wr[144 + c], fmaf(a.w, wr[216 + c], acc[c]))));
    }

    float4* zr = (float4*)(zh1 + row * 72);
#pragma unroll
    for (int kc = 0; kc < 18; ++kc)
        zr[kc] = make_float4(acc[4 * kc], acc[4 * kc + 1], acc[4 * kc + 2], acc[4 * kc + 3]);

    int slot = t & 31;
#pragma unroll
    for (int c = 0; c < 72; ++c) {
        atomicAdd(&ls[c * 33 + slot], acc[c]);
        atomicAdd(&ls[(72 + c) * 33 + slot], acc[c] * acc[c]);
    }
    __syncthreads();
    for (int c = t; c < 144; c += 256) {
        float s = 0.f;
        for (int q = 0; q < 32; ++q) s += ls[c * 33 + q];
        atomicAdd(&gstats[c * 16], s);
    }
}

// -------------------- kernel 4c: h_out, x_out --------------------
__global__ __launch_bounds__(256) void k_node2(
    const float* __restrict__ h, const float* __restrict__ x,
    const float* __restrict__ zh1,
    const float* __restrict__ Ah, const float* __restrict__ Bh,
    const float* __restrict__ Wh2, const float* __restrict__ bh2,
    const float* __restrict__ agg, const float* __restrict__ cnt,
    float* __restrict__ hout, float* __restrict__ xout)
{
    int row = blockIdx.x * 256 + threadIdx.x;   // < 4096
    float acc[72];
#pragma unroll
    for (int c = 0; c < 72; ++c) acc[c] = bh2[c];

    const float4* z4 = (const float4*)(zh1 + row * 72);
    for (int kc = 0; kc < 18; ++kc) {
        float4 v = z4[kc];
        int k0 = kc * 4;
        float z0 = fmaxf(fmaf(v.x, Ah[k0],     Bh[k0]),     0.f);
        float z1v = fmaxf(fmaf(v.y, Ah[k0 + 1], Bh[k0 + 1]), 0.f);
        float z2v = fmaxf(fmaf(v.z, Ah[k0 + 2], Bh[k0 + 2]), 0.f);
        float z3v = fmaxf(fmaf(v.w, Ah[k0 + 3], Bh[k0 + 3]), 0.f);
        const float* w0 = Wh2 + k0 * 72;
#pragma unroll
        for (int c = 0; c < 72; ++c)
            acc[c] = fmaf(z0, w0[c], fmaf(z1v, w0[72 + c], fmaf(z2v, w0[144 + c], fmaf(z3v, w0[216 + c], acc[c]))));
    }
    const float4* hr = (const float4*)(h + row * 72);
    float4* ho = (float4*)(hout + row * 72);
#pragma unroll
    for (int kc = 0; kc < 18; ++kc) {
        float4 hv = hr[kc];
        ho[kc] = make_float4(hv.x + acc[4 * kc], hv.y + acc[4 * kc + 1],
                             hv.z + acc[4 * kc + 2], hv.w + acc[4 * kc + 3]);
    }
    float inv = 1.f / fmaxf(cnt[row], 1.f);
    float4 xv = *(const float4*)(x + row * 4);
    float4 av = *(const float4*)(agg + row * 4);
    *(float4*)(xout + row * 4) = make_float4(xv.x + av.x * inv, xv.y + av.y * inv,
                                             xv.z + av.z * inv, xv.w + av.w * inv);
}

extern "C" void kernel_launch(void* const* d_in, const int* in_sizes, int n_in,
                              void* d_out, int out_size, void* d_ws, size_t ws_size,
                              hipStream_t stream) {
    const float* h    = (const float*)d_in[0];
    const float* x    = (const float*)d_in[1];
    const int*   ei   = (const int*)d_in[2];
    const int*   ej   = (const int*)d_in[3];
    const float* attr = (const float*)d_in[4];
    const float* We1  = (const float*)d_in[5];
    const float* ge   = (const float*)d_in[6];
    const float* bee  = (const float*)d_in[7];
    const float* We2  = (const float*)d_in[8];
    const float* be2  = (const float*)d_in[9];
    const float* Wm   = (const float*)d_in[10];
    const float* bm   = (const float*)d_in[11];
    const float* Wx1  = (const float*)d_in[12];
    const float* bx1  = (const float*)d_in[13];
    const float* Wx2  = (const float*)d_in[14];
    const float* Wh1  = (const float*)d_in[15];
    const float* bh1  = (const float*)d_in[16];
    const float* gh   = (const float*)d_in[17];
    const float* beh  = (const float*)d_in[18];
    const float* Wh2  = (const float*)d_in[19];
    const float* bh2  = (const float*)d_in[20];

    float* out  = (float*)d_out;
    float* hout = out + HOUT_OFF;
    float* xout = out + XOUT_OFF;
    float* m    = out + M_OFF;
    float* ws   = (float*)d_ws;

    hipMemsetAsync(ws, 0, (size_t)WS_ZERO_END * 4, stream);
    k_transpose<<<21, 256, 0, stream>>>(Wx1, ws + WS_WX1T);
    k_edge1<<<2048, 256, 0, stream>>>(h, x, ei, ej, We1, m, ws + WS_STATS_E);
    k_fin<<<1, 128, 0, stream>>>(ws + WS_STATS_E, ge, bee, ws + WS_AE, ws + WS_BE,
                                 1.0f / (float)(B_ * E_));
    k_edge2<<<512, 256, 0, stream>>>(x, ei, ej, We2, be2, Wm, bm, bx1, ws + WS_WX1T, Wx2,
                                     ws + WS_AE, ws + WS_BE, m,
                                     ws + WS_MAGG, ws + WS_AGG, ws + WS_CNT);
    k_node1<<<16, 256, 0, stream>>>(h, ws + WS_MAGG, attr, Wh1, bh1,
                                    ws + WS_ZH1, ws + WS_STATS_H);
    k_fin<<<1, 128, 0, stream>>>(ws + WS_STATS_H, gh, beh, ws + WS_AH, ws + WS_BH,
                                 1.0f / 4096.0f);
    k_node2<<<16, 256, 0, stream>>>(h, x, ws + WS_ZH1, ws + WS_AH, ws + WS_BH, Wh2, bh2,
                                    ws + WS_AGG, ws + WS_CNT, hout, xout);
}

// Round 6
// 1057.350 us; speedup vs baseline: 1.0548x; 1.0548x over previous
//
#include <hip/hip_runtime.h>
#include <math.h>

#define B_ 32
#define N_ 128
#define E_ 16384
#define EPS_ 1e-5f

// ---- ws layout (float offsets): IDENTICAL to round-0 proven layout ----
#define WS_STATS_E 0        // 144 accs, stride 16 floats (line-padded)
#define WS_STATS_H 2304
#define WS_MAGG    4608     // B*N*72  (doubles as P_mid before k_edge2v2)
#define WS_AGG     299520   // B*N*4
#define WS_CNT     315904   // B*N
#define WS_ZERO_END 320000
#define WS_AE      320000
#define WS_BE      320072
#define WS_AH      320144
#define WS_BH      320216
#define WS_WX1T    320288   // 72*72 transposed
#define WS_ZH1     325472   // B*N*72  (doubles as P_top before k_node1)
// total = 620384 floats == round-0 proven footprint

#define HOUT_OFF 0
#define XOUT_OFF 294912
#define M_OFF    311296

// -------------------- small prep: transpose W_x1 (round-0 verbatim) --------------------
__global__ void k_transpose(const float* __restrict__ Wx1, float* __restrict__ WT) {
    int idx = blockIdx.x * 256 + threadIdx.x;
    if (idx < 72 * 72) {
        int r = idx / 72, c = idx - r * 72;
        WT[c * 72 + r] = Wx1[idx];
    }
}

// -------------------- node projections: P_top = h@We1[0:72], P_mid = h@We1[72:144] ----
__global__ __launch_bounds__(256) void k_nodeproj(
    const float* __restrict__ h, const float* __restrict__ We1,
    float* __restrict__ Ptop, float* __restrict__ Pmid)
{
    int gid = blockIdx.x * 256 + threadIdx.x;   // < 8192
    int which = gid >> 12;                       // 0: top, 1: mid
    int row = gid & 4095;
    const float4* h4 = (const float4*)(h + (size_t)row * 72);
    const float* base = We1 + which * 5184;      // rows [0..71] or [72..143]
    float acc[72];
#pragma unroll
    for (int c = 0; c < 72; ++c) acc[c] = 0.f;
    for (int kc = 0; kc < 18; ++kc) {
        float4 a = h4[kc];
        const float* wr = base + (kc * 4) * 72;
#pragma unroll
        for (int c = 0; c < 72; ++c)
            acc[c] = fmaf(a.x, wr[c], fmaf(a.y, wr[72 + c], fmaf(a.z, wr[144 + c], fmaf(a.w, wr[216 + c], acc[c]))));
    }
    float* P = (which ? Pmid : Ptop) + (size_t)row * 72;
#pragma unroll
    for (int kc = 0; kc < 18; ++kc)
        *(float4*)(P + 4 * kc) = make_float4(acc[4 * kc], acc[4 * kc + 1], acc[4 * kc + 2], acc[4 * kc + 3]);
}

// -------------------- edge pass 1: z1 = Pt[i]+Pm[j]+norms*w144+dots*w145 (+BN stats) ----
__global__ __launch_bounds__(256) void k_edge1v2(
    const float* __restrict__ x,
    const int* __restrict__ ei, const int* __restrict__ ej,
    const float* __restrict__ Ptop, const float* __restrict__ Pmid,
    const float* __restrict__ We1,
    float* __restrict__ z1, float* __restrict__ gstats)
{
    __shared__ float ls[144 * 33];
    int t = threadIdx.x;
    for (int idx = t; idx < 144 * 33; idx += 256) ls[idx] = 0.f;
    __syncthreads();

    int eg = blockIdx.x * 256 + t;           // < 524288
    int b = eg >> 14;
    int i = ei[eg], j = ej[eg];
    int ri = b * N_ + i, rj = b * N_ + j;

    float4 xi = *(const float4*)(x + ri * 4);
    float4 xj = *(const float4*)(x + rj * 4);
    float xdx = xi.x - xj.x, xdy = xi.y - xj.y, xdz = xi.z - xj.z, xdw = xi.w - xj.w;
    float nsq = xdx * xdx - xdy * xdy - xdz * xdz - xdw * xdw;
    float dsq = xi.x * xj.x - xi.y * xj.y - xi.z * xj.z - xi.w * xj.w;
    float norms = copysignf(log1pf(fabsf(nsq)), nsq);
    float dots  = copysignf(log1pf(fabsf(dsq)), dsq);

    const float4* pt4 = (const float4*)(Ptop + (size_t)ri * 72);
    const float4* pm4 = (const float4*)(Pmid + (size_t)rj * 72);
    const float* w144 = We1 + 144 * 72;
    const float* w145 = We1 + 145 * 72;
    float4* zr = (float4*)(z1 + (size_t)eg * 72);

    int slot = t & 31;
#pragma unroll
    for (int kc = 0; kc < 18; ++kc) {
        float4 a = pt4[kc];
        float4 bq = pm4[kc];
        float4 wa = *(const float4*)(w144 + 4 * kc);
        float4 wb = *(const float4*)(w145 + 4 * kc);
        float4 r;
        r.x = fmaf(norms, wa.x, fmaf(dots, wb.x, a.x + bq.x));
        r.y = fmaf(norms, wa.y, fmaf(dots, wb.y, a.y + bq.y));
        r.z = fmaf(norms, wa.z, fmaf(dots, wb.z, a.z + bq.z));
        r.w = fmaf(norms, wa.w, fmaf(dots, wb.w, a.w + bq.w));
        zr[kc] = r;
        int c0 = 4 * kc;
        atomicAdd(&ls[(c0 + 0) * 33 + slot], r.x);
        atomicAdd(&ls[(c0 + 1) * 33 + slot], r.y);
        atomicAdd(&ls[(c0 + 2) * 33 + slot], r.z);
        atomicAdd(&ls[(c0 + 3) * 33 + slot], r.w);
        atomicAdd(&ls[(72 + c0 + 0) * 33 + slot], r.x * r.x);
        atomicAdd(&ls[(72 + c0 + 1) * 33 + slot], r.y * r.y);
        atomicAdd(&ls[(72 + c0 + 2) * 33 + slot], r.z * r.z);
        atomicAdd(&ls[(72 + c0 + 3) * 33 + slot], r.w * r.w);
    }
    __syncthreads();
    for (int c = t; c < 144; c += 256) {
        float s = 0.f;
        for (int q = 0; q < 32; ++q) s += ls[c * 33 + q];
        atomicAdd(&gstats[c * 16], s);
    }
}

// -------------------- BN finalize (round-0 verbatim, stride-16 stats) --------------------
__global__ void k_fin(const float* __restrict__ gstats, const float* __restrict__ g,
                      const float* __restrict__ be, float* __restrict__ A,
                      float* __restrict__ Bv, float Minv)
{
    int c = threadIdx.x;
    if (c < 72) {
        float s = gstats[c * 16], sq = gstats[(72 + c) * 16];
        float mu = s * Minv;
        float var = sq * Minv - mu * mu;
        float inv = rsqrtf(var + EPS_);
        float a = g[c] * inv;
        A[c] = a;
        Bv[c] = be[c] - mu * a;
    }
}

// -------------------- edge pass 2: LDS-staged weights, two phases --------------------
__global__ __launch_bounds__(256) void k_edge2v2(
    const float* __restrict__ x,
    const int* __restrict__ ei, const int* __restrict__ ej,
    const float* __restrict__ We2, const float* __restrict__ be2,
    const float* __restrict__ Wm, const float* __restrict__ bm,
    const float* __restrict__ bx1, const float* __restrict__ Wx1T,
    const float* __restrict__ Wx2,
    const float* __restrict__ Ae, const float* __restrict__ Be,
    float* m_out,                       // z1 in, m out (in place, same thread)
    float* __restrict__ magg, float* __restrict__ agg, float* __restrict__ cnt)
{
    __shared__ float WS[5184];          // one 72x72 weight matrix (We2, then Wx1T)
    __shared__ float lmagg[128 * 73];
    __shared__ float lagg[128 * 5];
    __shared__ float lcnt[128];
    int t = threadIdx.x;
    for (int idx = t; idx < 128 * 73; idx += 256) lmagg[idx] = 0.f;
    for (int idx = t; idx < 128 * 5; idx += 256) lagg[idx] = 0.f;
    if (t < 128) lcnt[t] = 0.f;
    for (int idx = t; idx < 1296; idx += 256)
        ((float4*)WS)[idx] = ((const float4*)We2)[idx];
    __syncthreads();

    int b = blockIdx.x >> 4;
    int chunk = blockIdx.x & 15;
    float bm0 = bm[0];

    // ---- phase A: m = sigmoid-gated relu(relu(BN(z1)) @ We2 + be2) ----
    for (int it = 0; it < 4; ++it) {
        int eg = b * E_ + chunk * 1024 + it * 256 + t;
        const float4* zrow = (const float4*)(m_out + (size_t)eg * 72);
        float4 acc4[18];
#pragma unroll
        for (int cc = 0; cc < 18; ++cc) acc4[cc] = *(const float4*)(be2 + cc * 4);

        for (int kc = 0; kc < 18; ++kc) {       // not unrolled: keep I$ small
            float4 v = zrow[kc];
            int k0 = kc * 4;
            float z0 = fmaxf(fmaf(v.x, Ae[k0 + 0], Be[k0 + 0]), 0.f);
            float z1v = fmaxf(fmaf(v.y, Ae[k0 + 1], Be[k0 + 1]), 0.f);
            float z2v = fmaxf(fmaf(v.z, Ae[k0 + 2], Be[k0 + 2]), 0.f);
            float z3v = fmaxf(fmaf(v.w, Ae[k0 + 3], Be[k0 + 3]), 0.f);
            const float* w0 = &WS[(k0 + 0) * 72];
            const float* w1 = &WS[(k0 + 1) * 72];
            const float* w2 = &WS[(k0 + 2) * 72];
            const float* w3 = &WS[(k0 + 3) * 72];
#pragma unroll
            for (int cc = 0; cc < 18; ++cc) {
                float4 a0 = *(const float4*)(w0 + cc * 4);
                float4 a1 = *(const float4*)(w1 + cc * 4);
                float4 a2 = *(const float4*)(w2 + cc * 4);
                float4 a3 = *(const float4*)(w3 + cc * 4);
                acc4[cc].x = fmaf(z0, a0.x, fmaf(z1v, a1.x, fmaf(z2v, a2.x, fmaf(z3v, a3.x, acc4[cc].x))));
                acc4[cc].y = fmaf(z0, a0.y, fmaf(z1v, a1.y, fmaf(z2v, a2.y, fmaf(z3v, a3.y, acc4[cc].y))));
                acc4[cc].z = fmaf(z0, a0.z, fmaf(z1v, a1.z, fmaf(z2v, a2.z, fmaf(z3v, a3.z, acc4[cc].z))));
                acc4[cc].w = fmaf(z0, a0.w, fmaf(z1v, a1.w, fmaf(z2v, a2.w, fmaf(z3v, a3.w, acc4[cc].w))));
            }
        }
        float wdot = bm0;
#pragma unroll
        for (int cc = 0; cc < 18; ++cc) {
            acc4[cc].x = fmaxf(acc4[cc].x, 0.f);
            acc4[cc].y = fmaxf(acc4[cc].y, 0.f);
            acc4[cc].z = fmaxf(acc4[cc].z, 0.f);
            acc4[cc].w = fmaxf(acc4[cc].w, 0.f);
            float4 wm4 = *(const float4*)(Wm + cc * 4);
            wdot = fmaf(acc4[cc].x, wm4.x, fmaf(acc4[cc].y, wm4.y,
                   fmaf(acc4[cc].z, wm4.z, fmaf(acc4[cc].w, wm4.w, wdot))));
        }
        float wsig = 1.f / (1.f + expf(-wdot));
        float4* mw = (float4*)(m_out + (size_t)eg * 72);
#pragma unroll
        for (int cc = 0; cc < 18; ++cc) {
            float4 r = acc4[cc];
            mw[cc] = make_float4(r.x * wsig, r.y * wsig, r.z * wsig, r.w * wsig);
        }
    }
    __syncthreads();
    for (int idx = t; idx < 1296; idx += 256)
        ((float4*)WS)[idx] = ((const float4*)Wx1T)[idx];
    __syncthreads();

    // ---- phase B: phi_x via Wx1T, trans clamp, segment sums ----
    for (int it = 0; it < 4; ++it) {
        int el = chunk * 1024 + it * 256 + t;
        int eg = b * E_ + el;
        int i = ei[eg], j = ej[eg];
        float4 xi = *(const float4*)(x + (b * N_ + i) * 4);
        float4 xj = *(const float4*)(x + (b * N_ + j) * 4);
        float xdx = xi.x - xj.x, xdy = xi.y - xj.y, xdz = xi.z - xj.z, xdw = xi.w - xj.w;

        float4 mv[18];
        const float4* mr = (const float4*)(m_out + (size_t)eg * 72);
#pragma unroll
        for (int cc = 0; cc < 18; ++cc) mv[cc] = mr[cc];

        float phix = 0.f;
        for (int c2c = 0; c2c < 18; ++c2c) {    // not unrolled
            int c20 = c2c * 4;
            float4 t4 = *(const float4*)(bx1 + c20);
            const float* w0 = &WS[(c20 + 0) * 72];
            const float* w1 = &WS[(c20 + 1) * 72];
            const float* w2 = &WS[(c20 + 2) * 72];
            const float* w3 = &WS[(c20 + 3) * 72];
#pragma unroll
            for (int cc = 0; cc < 18; ++cc) {
                float4 mvv = mv[cc];
                float4 a0 = *(const float4*)(w0 + cc * 4);
                float4 a1 = *(const float4*)(w1 + cc * 4);
                float4 a2 = *(const float4*)(w2 + cc * 4);
                float4 a3 = *(const float4*)(w3 + cc * 4);
                t4.x = fmaf(mvv.x, a0.x, fmaf(mvv.y, a0.y, fmaf(mvv.z, a0.z, fmaf(mvv.w, a0.w, t4.x))));
                t4.y = fmaf(mvv.x, a1.x, fmaf(mvv.y, a1.y, fmaf(mvv.z, a1.z, fmaf(mvv.w, a1.w, t4.y))));
                t4.z = fmaf(mvv.x, a2.x, fmaf(mvv.y, a2.y, fmaf(mvv.z, a2.z, fmaf(mvv.w, a2.w, t4.z))));
                t4.w = fmaf(mvv.x, a3.x, fmaf(mvv.y, a3.y, fmaf(mvv.z, a3.z, fmaf(mvv.w, a3.w, t4.w))));
            }
            float4 wx2v = *(const float4*)(Wx2 + c20);
            phix = fmaf(fmaxf(t4.x, 0.f), wx2v.x, phix);
            phix = fmaf(fmaxf(t4.y, 0.f), wx2v.y, phix);
            phix = fmaf(fmaxf(t4.z, 0.f), wx2v.z, phix);
            phix = fmaf(fmaxf(t4.w, 0.f), wx2v.w, phix);
        }
        float trx = fminf(fmaxf(xdx * phix, -100.f), 100.f);
        float try_ = fminf(fmaxf(xdy * phix, -100.f), 100.f);
        float trz = fminf(fmaxf(xdz * phix, -100.f), 100.f);
        float trw = fminf(fmaxf(xdw * phix, -100.f), 100.f);

        atomicAdd(&lcnt[i], 1.f);
        atomicAdd(&lagg[i * 5 + 0], trx);
        atomicAdd(&lagg[i * 5 + 1], try_);
        atomicAdd(&lagg[i * 5 + 2], trz);
        atomicAdd(&lagg[i * 5 + 3], trw);
        int base = i * 73;
#pragma unroll
        for (int cc = 0; cc < 18; ++cc) {
            atomicAdd(&lmagg[base + 4 * cc + 0], mv[cc].x);
            atomicAdd(&lmagg[base + 4 * cc + 1], mv[cc].y);
            atomicAdd(&lmagg[base + 4 * cc + 2], mv[cc].z);
            atomicAdd(&lmagg[base + 4 * cc + 3], mv[cc].w);
        }
    }
    __syncthreads();

    int nb = b * N_;
    for (int idx = t; idx < 128 * 72; idx += 256) {
        int n = idx / 72, c = idx - n * 72;
        float v = lmagg[n * 73 + c];
        if (v != 0.f) atomicAdd(&magg[(nb + n) * 72 + c], v);
    }
    for (int idx = t; idx < 128 * 4; idx += 256) {
        int n = idx >> 2, d = idx & 3;
        float v = lagg[n * 5 + d];
        if (v != 0.f) atomicAdd(&agg[(nb + n) * 4 + d], v);
    }
    if (t < 128) {
        float v = lcnt[t];
        if (v != 0.f) atomicAdd(&cnt[nb + t], v);
    }
}

// -------------------- round-0 k_node1 (verbatim, proven) --------------------
__global__ __launch_bounds__(256) void k_node1(
    const float* __restrict__ h, const float* __restrict__ magg,
    const float* __restrict__ attr, const float* __restrict__ Wh1,
    const float* __restrict__ bh1,
    float* __restrict__ zh1, float* __restrict__ gstats)
{
    __shared__ float ls[144 * 33];
    int t = threadIdx.x;
    for (int idx = t; idx < 144 * 33; idx += 256) ls[idx] = 0.f;
    __syncthreads();

    int row = blockIdx.x * 256 + t;   // < 4096
    float acc[72];
#pragma unroll
    for (int c = 0; c < 72; ++c) acc[c] = bh1[c];

    const float4* h4 = (const float4*)(h + row * 72);
    for (int kc = 0; kc < 18; ++kc) {
        float4 a = h4[kc];
        const float* wr = Wh1 + (kc * 4) * 72;
#pragma unroll
        for (int c = 0; c < 72; ++c)
            acc[c] = fmaf(a.x, wr[c], fmaf(a.y, wr[72 + c], fmaf(a.z, wr[144 + c], fmaf(a.w, wr[216 + c], acc[c]))));
    }
    const float4* mg4 = (const float4*)(magg + row * 72);
    for (int kc = 0; kc < 18; ++kc) {
        float4 a = mg4[kc];
        const float* wr = Wh1 + ((72 + kc * 4)) * 72;
#pragma unroll
        for (int c = 0; c < 72; ++c)
            acc[c] = fmaf(a.x, wr[c], fmaf(a.y, wr[72 + c], fmaf(a.z, wr[144 + c], fmaf(a.w, wr[216 + c], acc[c]))));
    }
    const float4* at4 = (const float4*)(attr + row * 8);
    for (int kc = 0; kc < 2; ++kc) {
        float4 a = at4[kc];
        const float* wr = Wh1 + ((144 + kc * 4)) * 72;
#pragma unroll
        for (int c = 0; c < 72; ++c)
            acc[c] = fmaf(a.x, wr[c], fmaf(a.y, wr[72 + c], fmaf(a.z, wr[144 + c], fmaf(a.w, wr[216 + c], acc[c]))));
    }

    float4* zr = (float4*)(zh1 + row * 72);
#pragma unroll
    for (int kc = 0; kc < 18; ++kc)
        zr[kc] = make_float4(acc[4 * kc], acc[4 * kc + 1], acc[4 * kc + 2], acc[4 * kc + 3]);

    int slot = t & 31;
#pragma unroll
    for (int c = 0; c < 72; ++c) {
        atomicAdd(&ls[c * 33 + slot], acc[c]);
        atomicAdd(&ls[(72 + c) * 33 + slot], acc[c] * acc[c]);
    }
    __syncthreads();
    for (int c = t; c < 144; c += 256) {
        float s = 0.f;
        for (int q = 0; q < 32; ++q) s += ls[c * 33 + q];
        atomicAdd(&gstats[c * 16], s);
    }
}

// -------------------- round-0 k_node2 (verbatim, proven) --------------------
__global__ __launch_bounds__(256) void k_node2(
    const float* __restrict__ h, const float* __restrict__ x,
    const float* __restrict__ zh1,
    const float* __restrict__ Ah, const float* __restrict__ Bh,
    const float* __restrict__ Wh2, const float* __restrict__ bh2,
    const float* __restrict__ agg, const float* __restrict__ cnt,
    float* __restrict__ hout, float* __restrict__ xout)
{
    int row = blockIdx.x * 256 + threadIdx.x;   // < 4096
    float acc[72];
#pragma unroll
    for (int c = 0; c < 72; ++c) acc[c] = bh2[c];

    const float4* z4 = (const float4*)(zh1 + row * 72);
    for (int kc = 0; kc < 18; ++kc) {
        float4 v = z4[kc];
        int k0 = kc * 4;
        float z0 = fmaxf(fmaf(v.x, Ah[k0],     Bh[k0]),     0.f);
        float z1v = fmaxf(fmaf(v.y, Ah[k0 + 1], Bh[k0 + 1]), 0.f);
        float z2v = fmaxf(fmaf(v.z, Ah[k0 + 2], Bh[k0 + 2]), 0.f);
        float z3v = fmaxf(fmaf(v.w, Ah[k0 + 3], Bh[k0 + 3]), 0.f);
        const float* w0 = Wh2 + k0 * 72;
#pragma unroll
        for (int c = 0; c < 72; ++c)
            acc[c] = fmaf(z0, w0[c], fmaf(z1v, w0[72 + c], fmaf(z2v, w0[144 + c], fmaf(z3v, w0[216 + c], acc[c]))));
    }
    const float4* hr = (const float4*)(h + row * 72);
    float4* ho = (float4*)(hout + row * 72);
#pragma unroll
    for (int kc = 0; kc < 18; ++kc) {
        float4 hv = hr[kc];
        ho[kc] = make_float4(hv.x + acc[4 * kc], hv.y + acc[4 * kc + 1],
                             hv.z + acc[4 * kc + 2], hv.w + acc[4 * kc + 3]);
    }
    float inv = 1.f / fmaxf(cnt[row], 1.f);
    float4 xv = *(const float4*)(x + row * 4);
    float4 av = *(const float4*)(agg + row * 4);
    *(float4*)(xout + row * 4) = make_float4(xv.x + av.x * inv, xv.y + av.y * inv,
                                             xv.z + av.z * inv, xv.w + av.w * inv);
}

extern "C" void kernel_launch(void* const* d_in, const int* in_sizes, int n_in,
                              void* d_out, int out_size, void* d_ws, size_t ws_size,
                              hipStream_t stream) {
    const float* h    = (const float*)d_in[0];
    const float* x    = (const float*)d_in[1];
    const int*   ei   = (const int*)d_in[2];
    const int*   ej   = (const int*)d_in[3];
    const float* attr = (const float*)d_in[4];
    const float* We1  = (const float*)d_in[5];
    const float* ge   = (const float*)d_in[6];
    const float* bee  = (const float*)d_in[7];
    const float* We2  = (const float*)d_in[8];
    const float* be2  = (const float*)d_in[9];
    const float* Wm   = (const float*)d_in[10];
    const float* bm   = (const float*)d_in[11];
    const float* Wx1  = (const float*)d_in[12];
    const float* bx1  = (const float*)d_in[13];
    const float* Wx2  = (const float*)d_in[14];
    const float* Wh1  = (const float*)d_in[15];
    const float* bh1  = (const float*)d_in[16];
    const float* gh   = (const float*)d_in[17];
    const float* beh  = (const float*)d_in[18];
    const float* Wh2  = (const float*)d_in[19];
    const float* bh2  = (const float*)d_in[20];

    float* out  = (float*)d_out;
    float* hout = out + HOUT_OFF;
    float* xout = out + XOUT_OFF;
    float* mz   = out + M_OFF;          // z1 (fp32), then m (fp32), in place
    float* ws   = (float*)d_ws;

    hipMemsetAsync(ws, 0, (size_t)WS_ZERO_END * 4, stream);
    k_transpose<<<21, 256, 0, stream>>>(Wx1, ws + WS_WX1T);
    // P_top lives in the (currently dead) ZH1 region; P_mid in the MAGG region
    k_nodeproj<<<32, 256, 0, stream>>>(h, We1, ws + WS_ZH1, ws + WS_MAGG);
    k_edge1v2<<<2048, 256, 0, stream>>>(x, ei, ej, ws + WS_ZH1, ws + WS_MAGG, We1,
                                        mz, ws + WS_STATS_E);
    k_fin<<<1, 128, 0, stream>>>(ws + WS_STATS_E, ge, bee, ws + WS_AE, ws + WS_BE,
                                 1.0f / (float)(B_ * E_));
    // re-zero magg (P_mid is dead now; k_edge2v2 atomically accumulates into it)
    hipMemsetAsync(ws + WS_MAGG, 0, (size_t)(B_ * N_ * 72) * 4, stream);
    k_edge2v2<<<512, 256, 0, stream>>>(x, ei, ej, We2, be2, Wm, bm, bx1, ws + WS_WX1T,
                                       Wx2, ws + WS_AE, ws + WS_BE, mz,
                                       ws + WS_MAGG, ws + WS_AGG, ws + WS_CNT);
    k_node1<<<16, 256, 0, stream>>>(h, ws + WS_MAGG, attr, Wh1, bh1,
                                    ws + WS_ZH1, ws + WS_STATS_H);
    k_fin<<<1, 128, 0, stream>>>(ws + WS_STATS_H, gh, beh, ws + WS_AH, ws + WS_BH,
                                 1.0f / 4096.0f);
    k_node2<<<16, 256, 0, stream>>>(h, x, ws + WS_ZH1, ws + WS_AH, ws + WS_BH, Wh2, bh2,
                                    ws + WS_AGG, ws + WS_CNT, hout, xout);
}

// Round 7
// 979.657 us; speedup vs baseline: 1.1385x; 1.0793x over previous
//
#include <hip/hip_runtime.h>
#include <math.h>

#define B_ 32
#define N_ 128
#define E_ 16384
#define EPS_ 1e-5f

// ---- ws layout (float offsets): IDENTICAL to round-0 proven layout ----
#define WS_STATS_E 0        // 144 accs, stride 16 floats (line-padded)
#define WS_STATS_H 2304
#define WS_MAGG    4608     // B*N*72  (doubles as P_mid before k_edge2v3)
#define WS_AGG     299520   // B*N*4
#define WS_CNT     315904   // B*N
#define WS_ZERO_END 320000
#define WS_AE      320000
#define WS_BE      320072
#define WS_AH      320144
#define WS_BH      320216
#define WS_WX1T    320288   // 72*72 transposed
#define WS_ZH1     325472   // B*N*72  (doubles as P_top before k_node1)
// total = 620384 floats == round-0 proven footprint

#define HOUT_OFF 0
#define XOUT_OFF 294912
#define M_OFF    311296

// -------------------- small prep: transpose W_x1 (round-0 verbatim) --------------------
__global__ void k_transpose(const float* __restrict__ Wx1, float* __restrict__ WT) {
    int idx = blockIdx.x * 256 + threadIdx.x;
    if (idx < 72 * 72) {
        int r = idx / 72, c = idx - r * 72;
        WT[c * 72 + r] = Wx1[idx];
    }
}

// ---- node projections: P_top = h@We1[0:72], P_mid = h@We1[72:144], c-quartered ----
__global__ __launch_bounds__(256) void k_nodeproj(
    const float* __restrict__ h, const float* __restrict__ We1,
    float* __restrict__ Ptop, float* __restrict__ Pmid)
{
    int gid = blockIdx.x * 256 + threadIdx.x;    // < 32768
    int which = gid >> 14;                        // 0: top, 1: mid
    int rem = gid & 16383;
    int row = rem >> 2;                           // 4096 rows
    int q = rem & 3;                              // c-quarter
    int c0 = q * 18;
    const float4* h4 = (const float4*)(h + (size_t)row * 72);
    const float* base = We1 + which * 5184 + c0;
    float acc[18];
#pragma unroll
    for (int c = 0; c < 18; ++c) acc[c] = 0.f;
    for (int kc = 0; kc < 18; ++kc) {
        float4 a = h4[kc];
        const float* wr = base + (kc * 4) * 72;
#pragma unroll
        for (int c = 0; c < 18; ++c)
            acc[c] = fmaf(a.x, wr[c], fmaf(a.y, wr[72 + c], fmaf(a.z, wr[144 + c], fmaf(a.w, wr[216 + c], acc[c]))));
    }
    float* P = (which ? Pmid : Ptop) + (size_t)row * 72 + c0;
#pragma unroll
    for (int c = 0; c < 18; ++c) P[c] = acc[c];
}

// -------------------- edge pass 1: z1 = Pt[i]+Pm[j]+norms*w144+dots*w145 (+BN stats) ----
__global__ __launch_bounds__(256) void k_edge1v2(
    const float* __restrict__ x,
    const int* __restrict__ ei, const int* __restrict__ ej,
    const float* __restrict__ Ptop, const float* __restrict__ Pmid,
    const float* __restrict__ We1,
    float* __restrict__ z1, float* __restrict__ gstats)
{
    __shared__ float ls[144 * 33];
    int t = threadIdx.x;
    for (int idx = t; idx < 144 * 33; idx += 256) ls[idx] = 0.f;
    __syncthreads();

    int eg = blockIdx.x * 256 + t;           // < 524288
    int b = eg >> 14;
    int i = ei[eg], j = ej[eg];
    int ri = b * N_ + i, rj = b * N_ + j;

    float4 xi = *(const float4*)(x + ri * 4);
    float4 xj = *(const float4*)(x + rj * 4);
    float xdx = xi.x - xj.x, xdy = xi.y - xj.y, xdz = xi.z - xj.z, xdw = xi.w - xj.w;
    float nsq = xdx * xdx - xdy * xdy - xdz * xdz - xdw * xdw;
    float dsq = xi.x * xj.x - xi.y * xj.y - xi.z * xj.z - xi.w * xj.w;
    float norms = copysignf(log1pf(fabsf(nsq)), nsq);
    float dots  = copysignf(log1pf(fabsf(dsq)), dsq);

    const float4* pt4 = (const float4*)(Ptop + (size_t)ri * 72);
    const float4* pm4 = (const float4*)(Pmid + (size_t)rj * 72);
    const float* w144 = We1 + 144 * 72;
    const float* w145 = We1 + 145 * 72;
    float4* zr = (float4*)(z1 + (size_t)eg * 72);

    int slot = t & 31;
#pragma unroll
    for (int kc = 0; kc < 18; ++kc) {
        float4 a = pt4[kc];
        float4 bq = pm4[kc];
        float4 wa = *(const float4*)(w144 + 4 * kc);
        float4 wb = *(const float4*)(w145 + 4 * kc);
        float4 r;
        r.x = fmaf(norms, wa.x, fmaf(dots, wb.x, a.x + bq.x));
        r.y = fmaf(norms, wa.y, fmaf(dots, wb.y, a.y + bq.y));
        r.z = fmaf(norms, wa.z, fmaf(dots, wb.z, a.z + bq.z));
        r.w = fmaf(norms, wa.w, fmaf(dots, wb.w, a.w + bq.w));
        zr[kc] = r;
        int c0 = 4 * kc;
        atomicAdd(&ls[(c0 + 0) * 33 + slot], r.x);
        atomicAdd(&ls[(c0 + 1) * 33 + slot], r.y);
        atomicAdd(&ls[(c0 + 2) * 33 + slot], r.z);
        atomicAdd(&ls[(c0 + 3) * 33 + slot], r.w);
        atomicAdd(&ls[(72 + c0 + 0) * 33 + slot], r.x * r.x);
        atomicAdd(&ls[(72 + c0 + 1) * 33 + slot], r.y * r.y);
        atomicAdd(&ls[(72 + c0 + 2) * 33 + slot], r.z * r.z);
        atomicAdd(&ls[(72 + c0 + 3) * 33 + slot], r.w * r.w);
    }
    __syncthreads();
    for (int c = t; c < 144; c += 256) {
        float s = 0.f;
        for (int q = 0; q < 32; ++q) s += ls[c * 33 + q];
        atomicAdd(&gstats[c * 16], s);
    }
}

// -------------------- BN finalize (round-0 verbatim, stride-16 stats) --------------------
__global__ void k_fin(const float* __restrict__ gstats, const float* __restrict__ g,
                      const float* __restrict__ be, float* __restrict__ A,
                      float* __restrict__ Bv, float Minv)
{
    int c = threadIdx.x;
    if (c < 72) {
        float s = gstats[c * 16], sq = gstats[(72 + c) * 16];
        float mu = s * Minv;
        float var = sq * Minv - mu * mu;
        float inv = rsqrtf(var + EPS_);
        float a = g[c] * inv;
        A[c] = a;
        Bv[c] = be[c] - mu * a;
    }
}

// -------------------- edge pass 2 (ET=2): LDS weights amortized over 2 edges ----------
__global__ __launch_bounds__(256, 2) void k_edge2v3(
    const float* __restrict__ x,
    const int* __restrict__ ei, const int* __restrict__ ej,
    const float* __restrict__ We2, const float* __restrict__ be2,
    const float* __restrict__ Wm, const float* __restrict__ bm,
    const float* __restrict__ bx1, const float* __restrict__ Wx1T,
    const float* __restrict__ Wx2,
    const float* __restrict__ Ae, const float* __restrict__ Be,
    float* m_out,                       // z1 in, m out (in place, same thread)
    float* __restrict__ magg, float* __restrict__ agg, float* __restrict__ cnt)
{
    __shared__ float WS[5184];          // one 72x72 weight matrix (We2, then Wx1T)
    __shared__ float lmagg[128 * 73];
    __shared__ float lagg[128 * 5];
    __shared__ float lcnt[128];
    int t = threadIdx.x;
    for (int idx = t; idx < 128 * 73; idx += 256) lmagg[idx] = 0.f;
    for (int idx = t; idx < 128 * 5; idx += 256) lagg[idx] = 0.f;
    if (t < 128) lcnt[t] = 0.f;
    for (int idx = t; idx < 1296; idx += 256)
        ((float4*)WS)[idx] = ((const float4*)We2)[idx];
    __syncthreads();

    int b = blockIdx.x >> 5;
    int chunk = blockIdx.x & 31;
    int eg0 = b * E_ + chunk * 512 + t;
    int eg1 = eg0 + 256;
    float bm0 = bm[0];

    // ---- phase A: m = sigmoid-gated relu(relu(BN(z1)) @ We2 + be2), both edges ----
    const float4* zr0 = (const float4*)(m_out + (size_t)eg0 * 72);
    const float4* zr1 = (const float4*)(m_out + (size_t)eg1 * 72);
    float4 acc0[18], acc1[18];
#pragma unroll
    for (int cc = 0; cc < 18; ++cc) {
        float4 bv = *(const float4*)(be2 + cc * 4);
        acc0[cc] = bv; acc1[cc] = bv;
    }
    for (int kc = 0; kc < 18; ++kc) {           // not unrolled: keep I$ small
        float4 v0 = zr0[kc];
        float4 v1 = zr1[kc];
        int k0 = kc * 4;
        float4 A4 = *(const float4*)(Ae + k0);
        float4 B4 = *(const float4*)(Be + k0);
        float za0 = fmaxf(fmaf(v0.x, A4.x, B4.x), 0.f);
        float za1 = fmaxf(fmaf(v0.y, A4.y, B4.y), 0.f);
        float za2 = fmaxf(fmaf(v0.z, A4.z, B4.z), 0.f);
        float za3 = fmaxf(fmaf(v0.w, A4.w, B4.w), 0.f);
        float zb0 = fmaxf(fmaf(v1.x, A4.x, B4.x), 0.f);
        float zb1 = fmaxf(fmaf(v1.y, A4.y, B4.y), 0.f);
        float zb2 = fmaxf(fmaf(v1.z, A4.z, B4.z), 0.f);
        float zb3 = fmaxf(fmaf(v1.w, A4.w, B4.w), 0.f);
        const float* w0 = &WS[(k0 + 0) * 72];
        const float* w1 = &WS[(k0 + 1) * 72];
        const float* w2 = &WS[(k0 + 2) * 72];
        const float* w3 = &WS[(k0 + 3) * 72];
#pragma unroll
        for (int cc = 0; cc < 18; ++cc) {
            float4 a0 = *(const float4*)(w0 + cc * 4);
            float4 a1 = *(const float4*)(w1 + cc * 4);
            float4 a2 = *(const float4*)(w2 + cc * 4);
            float4 a3 = *(const float4*)(w3 + cc * 4);
            acc0[cc].x = fmaf(za0, a0.x, fmaf(za1, a1.x, fmaf(za2, a2.x, fmaf(za3, a3.x, acc0[cc].x))));
            acc0[cc].y = fmaf(za0, a0.y, fmaf(za1, a1.y, fmaf(za2, a2.y, fmaf(za3, a3.y, acc0[cc].y))));
            acc0[cc].z = fmaf(za0, a0.z, fmaf(za1, a1.z, fmaf(za2, a2.z, fmaf(za3, a3.z, acc0[cc].z))));
            acc0[cc].w = fmaf(za0, a0.w, fmaf(za1, a1.w, fmaf(za2, a2.w, fmaf(za3, a3.w, acc0[cc].w))));
            acc1[cc].x = fmaf(zb0, a0.x, fmaf(zb1, a1.x, fmaf(zb2, a2.x, fmaf(zb3, a3.x, acc1[cc].x))));
            acc1[cc].y = fmaf(zb0, a0.y, fmaf(zb1, a1.y, fmaf(zb2, a2.y, fmaf(zb3, a3.y, acc1[cc].y))));
            acc1[cc].z = fmaf(zb0, a0.z, fmaf(zb1, a1.z, fmaf(zb2, a2.z, fmaf(zb3, a3.z, acc1[cc].z))));
            acc1[cc].w = fmaf(zb0, a0.w, fmaf(zb1, a1.w, fmaf(zb2, a2.w, fmaf(zb3, a3.w, acc1[cc].w))));
        }
    }
    float wdot0 = bm0, wdot1 = bm0;
#pragma unroll
    for (int cc = 0; cc < 18; ++cc) {
        acc0[cc].x = fmaxf(acc0[cc].x, 0.f); acc0[cc].y = fmaxf(acc0[cc].y, 0.f);
        acc0[cc].z = fmaxf(acc0[cc].z, 0.f); acc0[cc].w = fmaxf(acc0[cc].w, 0.f);
        acc1[cc].x = fmaxf(acc1[cc].x, 0.f); acc1[cc].y = fmaxf(acc1[cc].y, 0.f);
        acc1[cc].z = fmaxf(acc1[cc].z, 0.f); acc1[cc].w = fmaxf(acc1[cc].w, 0.f);
        float4 wm4 = *(const float4*)(Wm + cc * 4);
        wdot0 = fmaf(acc0[cc].x, wm4.x, fmaf(acc0[cc].y, wm4.y,
                fmaf(acc0[cc].z, wm4.z, fmaf(acc0[cc].w, wm4.w, wdot0))));
        wdot1 = fmaf(acc1[cc].x, wm4.x, fmaf(acc1[cc].y, wm4.y,
                fmaf(acc1[cc].z, wm4.z, fmaf(acc1[cc].w, wm4.w, wdot1))));
    }
    float sig0 = 1.f / (1.f + expf(-wdot0));
    float sig1 = 1.f / (1.f + expf(-wdot1));
    {
        float4* mw0 = (float4*)(m_out + (size_t)eg0 * 72);
        float4* mw1 = (float4*)(m_out + (size_t)eg1 * 72);
#pragma unroll
        for (int cc = 0; cc < 18; ++cc) {
            acc0[cc].x *= sig0; acc0[cc].y *= sig0; acc0[cc].z *= sig0; acc0[cc].w *= sig0;
            acc1[cc].x *= sig1; acc1[cc].y *= sig1; acc1[cc].z *= sig1; acc1[cc].w *= sig1;
            mw0[cc] = acc0[cc];
            mw1[cc] = acc1[cc];
        }
    }
    __syncthreads();
    for (int idx = t; idx < 1296; idx += 256)
        ((float4*)WS)[idx] = ((const float4*)Wx1T)[idx];
    __syncthreads();

    // ---- phase B: phi_x via Wx1T (m retained in acc0/acc1), trans, segment sums ----
    int i0 = ei[eg0], j0 = ej[eg0];
    int i1 = ei[eg1], j1 = ej[eg1];
    float4 xi0 = *(const float4*)(x + (b * N_ + i0) * 4);
    float4 xj0 = *(const float4*)(x + (b * N_ + j0) * 4);
    float4 xi1 = *(const float4*)(x + (b * N_ + i1) * 4);
    float4 xj1 = *(const float4*)(x + (b * N_ + j1) * 4);

    float phix0 = 0.f, phix1 = 0.f;
    for (int c2c = 0; c2c < 18; ++c2c) {        // not unrolled
        int c20 = c2c * 4;
        float4 t0 = *(const float4*)(bx1 + c20);
        float4 t1 = t0;
        const float* w0 = &WS[(c20 + 0) * 72];
        const float* w1 = &WS[(c20 + 1) * 72];
        const float* w2 = &WS[(c20 + 2) * 72];
        const float* w3 = &WS[(c20 + 3) * 72];
#pragma unroll
        for (int cc = 0; cc < 18; ++cc) {
            float4 a0 = *(const float4*)(w0 + cc * 4);
            float4 a1 = *(const float4*)(w1 + cc * 4);
            float4 a2 = *(const float4*)(w2 + cc * 4);
            float4 a3 = *(const float4*)(w3 + cc * 4);
            float4 m0 = acc0[cc];
            float4 m1 = acc1[cc];
            t0.x = fmaf(m0.x, a0.x, fmaf(m0.y, a0.y, fmaf(m0.z, a0.z, fmaf(m0.w, a0.w, t0.x))));
            t0.y = fmaf(m0.x, a1.x, fmaf(m0.y, a1.y, fmaf(m0.z, a1.z, fmaf(m0.w, a1.w, t0.y))));
            t0.z = fmaf(m0.x, a2.x, fmaf(m0.y, a2.y, fmaf(m0.z, a2.z, fmaf(m0.w, a2.w, t0.z))));
            t0.w = fmaf(m0.x, a3.x, fmaf(m0.y, a3.y, fmaf(m0.z, a3.z, fmaf(m0.w, a3.w, t0.w))));
            t1.x = fmaf(m1.x, a0.x, fmaf(m1.y, a0.y, fmaf(m1.z, a0.z, fmaf(m1.w, a0.w, t1.x))));
            t1.y = fmaf(m1.x, a1.x, fmaf(m1.y, a1.y, fmaf(m1.z, a1.z, fmaf(m1.w, a1.w, t1.y))));
            t1.z = fmaf(m1.x, a2.x, fmaf(m1.y, a2.y, fmaf(m1.z, a2.z, fmaf(m1.w, a2.w, t1.z))));
            t1.w = fmaf(m1.x, a3.x, fmaf(m1.y, a3.y, fmaf(m1.z, a3.z, fmaf(m1.w, a3.w, t1.w))));
        }
        float4 wx2v = *(const float4*)(Wx2 + c20);
        phix0 = fmaf(fmaxf(t0.x, 0.f), wx2v.x, phix0);
        phix0 = fmaf(fmaxf(t0.y, 0.f), wx2v.y, phix0);
        phix0 = fmaf(fmaxf(t0.z, 0.f), wx2v.z, phix0);
        phix0 = fmaf(fmaxf(t0.w, 0.f), wx2v.w, phix0);
        phix1 = fmaf(fmaxf(t1.x, 0.f), wx2v.x, phix1);
        phix1 = fmaf(fmaxf(t1.y, 0.f), wx2v.y, phix1);
        phix1 = fmaf(fmaxf(t1.z, 0.f), wx2v.z, phix1);
        phix1 = fmaf(fmaxf(t1.w, 0.f), wx2v.w, phix1);
    }
    {
        float trx = fminf(fmaxf((xi0.x - xj0.x) * phix0, -100.f), 100.f);
        float try_ = fminf(fmaxf((xi0.y - xj0.y) * phix0, -100.f), 100.f);
        float trz = fminf(fmaxf((xi0.z - xj0.z) * phix0, -100.f), 100.f);
        float trw = fminf(fmaxf((xi0.w - xj0.w) * phix0, -100.f), 100.f);
        atomicAdd(&lcnt[i0], 1.f);
        atomicAdd(&lagg[i0 * 5 + 0], trx);
        atomicAdd(&lagg[i0 * 5 + 1], try_);
        atomicAdd(&lagg[i0 * 5 + 2], trz);
        atomicAdd(&lagg[i0 * 5 + 3], trw);
        int base = i0 * 73;
#pragma unroll
        for (int cc = 0; cc < 18; ++cc) {
            atomicAdd(&lmagg[base + 4 * cc + 0], acc0[cc].x);
            atomicAdd(&lmagg[base + 4 * cc + 1], acc0[cc].y);
            atomicAdd(&lmagg[base + 4 * cc + 2], acc0[cc].z);
            atomicAdd(&lmagg[base + 4 * cc + 3], acc0[cc].w);
        }
    }
    {
        float trx = fminf(fmaxf((xi1.x - xj1.x) * phix1, -100.f), 100.f);
        float try_ = fminf(fmaxf((xi1.y - xj1.y) * phix1, -100.f), 100.f);
        float trz = fminf(fmaxf((xi1.z - xj1.z) * phix1, -100.f), 100.f);
        float trw = fminf(fmaxf((xi1.w - xj1.w) * phix1, -100.f), 100.f);
        atomicAdd(&lcnt[i1], 1.f);
        atomicAdd(&lagg[i1 * 5 + 0], trx);
        atomicAdd(&lagg[i1 * 5 + 1], try_);
        atomicAdd(&lagg[i1 * 5 + 2], trz);
        atomicAdd(&lagg[i1 * 5 + 3], trw);
        int base = i1 * 73;
#pragma unroll
        for (int cc = 0; cc < 18; ++cc) {
            atomicAdd(&lmagg[base + 4 * cc + 0], acc1[cc].x);
            atomicAdd(&lmagg[base + 4 * cc + 1], acc1[cc].y);
            atomicAdd(&lmagg[base + 4 * cc + 2], acc1[cc].z);
            atomicAdd(&lmagg[base + 4 * cc + 3], acc1[cc].w);
        }
    }
    __syncthreads();

    int nb = b * N_;
    for (int idx = t; idx < 128 * 72; idx += 256) {
        int n = idx / 72, c = idx - n * 72;
        float v = lmagg[n * 73 + c];
        if (v != 0.f) atomicAdd(&magg[(nb + n) * 72 + c], v);
    }
    for (int idx = t; idx < 128 * 4; idx += 256) {
        int n = idx >> 2, d = idx & 3;
        float v = lagg[n * 5 + d];
        if (v != 0.f) atomicAdd(&agg[(nb + n) * 4 + d], v);
    }
    if (t < 128) {
        float v = lcnt[t];
        if (v != 0.f) atomicAdd(&cnt[nb + t], v);
    }
}

// -------------------- round-0 k_node1 (verbatim, proven) --------------------
__global__ __launch_bounds__(256) void k_node1(
    const float* __restrict__ h, const float* __restrict__ magg,
    const float* __restrict__ attr, const float* __restrict__ Wh1,
    const float* __restrict__ bh1,
    float* __restrict__ zh1, float* __restrict__ gstats)
{
    __shared__ float ls[144 * 33];
    int t = threadIdx.x;
    for (int idx = t; idx < 144 * 33; idx += 256) ls[idx] = 0.f;
    __syncthreads();

    int row = blockIdx.x * 256 + t;   // < 4096
    float acc[72];
#pragma unroll
    for (int c = 0; c < 72; ++c) acc[c] = bh1[c];

    const float4* h4 = (const float4*)(h + row * 72);
    for (int kc = 0; kc < 18; ++kc) {
        float4 a = h4[kc];
        const float* wr = Wh1 + (kc * 4) * 72;
#pragma unroll
        for (int c = 0; c < 72; ++c)
            acc[c] = fmaf(a.x, wr[c], fmaf(a.y, wr[72 + c], fmaf(a.z, wr[144 + c], fmaf(a.w, wr[216 + c], acc[c]))));
    }
    const float4* mg4 = (const float4*)(magg + row * 72);
    for (int kc = 0; kc < 18; ++kc) {
        float4 a = mg4[kc];
        const float* wr = Wh1 + ((72 + kc * 4)) * 72;
#pragma unroll
        for (int c = 0; c < 72; ++c)
            acc[c] = fmaf(a.x, wr[c], fmaf(a.y, wr[72 + c], fmaf(a.z, wr[144 + c], fmaf(a.w, wr[216 + c], acc[c]))));
    }
    const float4* at4 = (const float4*)(attr + row * 8);
    for (int kc = 0; kc < 2; ++kc) {
        float4 a = at4[kc];
        const float* wr = Wh1 + ((144 + kc * 4)) * 72;
#pragma unroll
        for (int c = 0; c < 72; ++c)
            acc[c] = fmaf(a.x, wr[c], fmaf(a.y, wr[72 + c], fmaf(a.z, wr[144 + c], fmaf(a.w, wr[216 + c], acc[c]))));
    }

    float4* zr = (float4*)(zh1 + row * 72);
#pragma unroll
    for (int kc = 0; kc < 18; ++kc)
        zr[kc] = make_float4(acc[4 * kc], acc[4 * kc + 1], acc[4 * kc + 2], acc[4 * kc + 3]);

    int slot = t & 31;
#pragma unroll
    for (int c = 0; c < 72; ++c) {
        atomicAdd(&ls[c * 33 + slot], acc[c]);
        atomicAdd(&ls[(72 + c) * 33 + slot], acc[c] * acc[c]);
    }
    __syncthreads();
    for (int c = t; c < 144; c += 256) {
        float s = 0.f;
        for (int q = 0; q < 32; ++q) s += ls[c * 33 + q];
        atomicAdd(&gstats[c * 16], s);
    }
}

// -------------------- round-0 k_node2 (verbatim, proven) --------------------
__global__ __launch_bounds__(256) void k_node2(
    const float* __restrict__ h, const float* __restrict__ x,
    const float* __restrict__ zh1,
    const float* __restrict__ Ah, const float* __restrict__ Bh,
    const float* __restrict__ Wh2, const float* __restrict__ bh2,
    const float* __restrict__ agg, const float* __restrict__ cnt,
    float* __restrict__ hout, float* __restrict__ xout)
{
    int row = blockIdx.x * 256 + threadIdx.x;   // < 4096
    float acc[72];
#pragma unroll
    for (int c = 0; c < 72; ++c) acc[c] = bh2[c];

    const float4* z4 = (const float4*)(zh1 + row * 72);
    for (int kc = 0; kc < 18; ++kc) {
        float4 v = z4[kc];
        int k0 = kc * 4;
        float z0 = fmaxf(fmaf(v.x, Ah[k0],     Bh[k0]),     0.f);
        float z1v = fmaxf(fmaf(v.y, Ah[k0 + 1], Bh[k0 + 1]), 0.f);
        float z2v = fmaxf(fmaf(v.z, Ah[k0 + 2], Bh[k0 + 2]), 0.f);
        float z3v = fmaxf(fmaf(v.w, Ah[k0 + 3], Bh[k0 + 3]), 0.f);
        const float* w0 = Wh2 + k0 * 72;
#pragma unroll
        for (int c = 0; c < 72; ++c)
            acc[c] = fmaf(z0, w0[c], fmaf(z1v, w0[72 + c], fmaf(z2v, w0[144 + c], fmaf(z3v, w0[216 + c], acc[c]))));
    }
    const float4* hr = (const float4*)(h + row * 72);
    float4* ho = (float4*)(hout + row * 72);
#pragma unroll
    for (int kc = 0; kc < 18; ++kc) {
        float4 hv = hr[kc];
        ho[kc] = make_float4(hv.x + acc[4 * kc], hv.y + acc[4 * kc + 1],
                             hv.z + acc[4 * kc + 2], hv.w + acc[4 * kc + 3]);
    }
    float inv = 1.f / fmaxf(cnt[row], 1.f);
    float4 xv = *(const float4*)(x + row * 4);
    float4 av = *(const float4*)(agg + row * 4);
    *(float4*)(xout + row * 4) = make_float4(xv.x + av.x * inv, xv.y + av.y * inv,
                                             xv.z + av.z * inv, xv.w + av.w * inv);
}

extern "C" void kernel_launch(void* const* d_in, const int* in_sizes, int n_in,
                              void* d_out, int out_size, void* d_ws, size_t ws_size,
                              hipStream_t stream) {
    const float* h    = (const float*)d_in[0];
    const float* x    = (const float*)d_in[1];
    const int*   ei   = (const int*)d_in[2];
    const int*   ej   = (const int*)d_in[3];
    const float* attr = (const float*)d_in[4];
    const float* We1  = (const float*)d_in[5];
    const float* ge   = (const float*)d_in[6];
    const float* bee  = (const float*)d_in[7];
    const float* We2  = (const float*)d_in[8];
    const float* be2  = (const float*)d_in[9];
    const float* Wm   = (const float*)d_in[10];
    const float* bm   = (const float*)d_in[11];
    const float* Wx1  = (const float*)d_in[12];
    const float* bx1  = (const float*)d_in[13];
    const float* Wx2  = (const float*)d_in[14];
    const float* Wh1  = (const float*)d_in[15];
    const float* bh1  = (const float*)d_in[16];
    const float* gh   = (const float*)d_in[17];
    const float* beh  = (const float*)d_in[18];
    const float* Wh2  = (const float*)d_in[19];
    const float* bh2  = (const float*)d_in[20];

    float* out  = (float*)d_out;
    float* hout = out + HOUT_OFF;
    float* xout = out + XOUT_OFF;
    float* mz   = out + M_OFF;          // z1 (fp32), then m (fp32), in place
    float* ws   = (float*)d_ws;

    hipMemsetAsync(ws, 0, (size_t)WS_ZERO_END * 4, stream);
    k_transpose<<<21, 256, 0, stream>>>(Wx1, ws + WS_WX1T);
    // P_top lives in the (currently dead) ZH1 region; P_mid in the MAGG region
    k_nodeproj<<<128, 256, 0, stream>>>(h, We1, ws + WS_ZH1, ws + WS_MAGG);
    k_edge1v2<<<2048, 256, 0, stream>>>(x, ei, ej, ws + WS_ZH1, ws + WS_MAGG, We1,
                                        mz, ws + WS_STATS_E);
    k_fin<<<1, 128, 0, stream>>>(ws + WS_STATS_E, ge, bee, ws + WS_AE, ws + WS_BE,
                                 1.0f / (float)(B_ * E_));
    // re-zero magg (P_mid is dead now; k_edge2v3 atomically accumulates into it)
    hipMemsetAsync(ws + WS_MAGG, 0, (size_t)(B_ * N_ * 72) * 4, stream);
    k_edge2v3<<<1024, 256, 0, stream>>>(x, ei, ej, We2, be2, Wm, bm, bx1, ws + WS_WX1T,
                                        Wx2, ws + WS_AE, ws + WS_BE, mz,
                                        ws + WS_MAGG, ws + WS_AGG, ws + WS_CNT);
    k_node1<<<16, 256, 0, stream>>>(h, ws + WS_MAGG, attr, Wh1, bh1,
                                    ws + WS_ZH1, ws + WS_STATS_H);
    k_fin<<<1, 128, 0, stream>>>(ws + WS_STATS_H, gh, beh, ws + WS_AH, ws + WS_BH,
                                 1.0f / 4096.0f);
    k_node2<<<16, 256, 0, stream>>>(h, x, ws + WS_ZH1, ws + WS_AH, ws + WS_BH, Wh2, bh2,
                                    ws + WS_AGG, ws + WS_CNT, hout, xout);
}